// Round 11
// baseline (73.109 us; speedup 1.0000x reference)
//
#include <hip/hip_runtime.h>

// Maj3 via 4-class reformulation + MFMA (verified R7/R8):
//   clip(w1x1+w2x2+w3x3) = w1 * clip(x1 + (w1w2)x2 + (w1w3)x3),  w in {+-1}
//   y[n, G*4+q] = clip(x1 +- x2 +- x3)   (fp16);  M[a, G*4+q] = w1 or 0
//   out[n,a] = 3 * sum_k y[n,k] * M[k,a]   -> 16x16x32 f16 MFMA, K=768
// R11: single-dispatch fusion, take 2. R10 failed (absmax 175) with the
// af math provably identical to prep -> suspect register-pressure edge
// (~240 live VGPR at the 256 cap). This version: 3-chunk pipeline (peak
// ~150 VGPR), prep's exact float-ternary M logic (no bit tricks), and
// the R8-identical structure up to barrier 2 except chunk-0 w loads
// issued pre-barrier (hide under phase A).

typedef unsigned int u32;
typedef float f4 __attribute__((ext_vector_type(4)));
typedef float f2v __attribute__((ext_vector_type(2)));
typedef _Float16 h8 __attribute__((ext_vector_type(8)));
typedef __fp16 hp2 __attribute__((ext_vector_type(2)));
typedef u32 uu2 __attribute__((ext_vector_type(2)));
typedef int i4 __attribute__((ext_vector_type(4)));

#define HS    19            // h-stride (words) in x tile: odd -> no conflicts
#define PLANE (64 * HS)     // 1216 words per w-plane
#define NP    16            // positions per block

__device__ __forceinline__ float clip1(float s) {
    return __builtin_amdgcn_fmed3f(s, -1.0f, 1.0f);
}

// yb index for (G, p): [(G/2)][p][ (G&1)*2 + {0,1} ]
__device__ __forceinline__ int ybi(int G, int p) {
    return ((G >> 1) * NP + p) * 4 + (G & 1) * 2;
}

// EXACT prep-kernel logic (verified R7/R8), one G: M pair {lo, hi}.
__device__ __forceinline__ void mk_float(float w1, float w2, float w3,
                                         u32& lo, u32& hi) {
    const int q  = ((w1 * w2 < 0.f) ? 2 : 0) + ((w1 * w3 < 0.f) ? 1 : 0);
    const u32 s1 = (w1 < 0.f) ? 0xBC00u : 0x3C00u;   // fp16 -1 : +1
    const u32 v0 = (q == 0) ? s1 : 0u, v1 = (q == 1) ? s1 : 0u;
    const u32 v2 = (q == 2) ? s1 : 0u, v3 = (q == 3) ? s1 : 0u;
    lo = v0 | (v1 << 16);
    hi = v2 | (v3 << 16);
}

// load chunk g: 8 steps (st = g*8+t), 3 f2v each, offsets compile-time
__device__ __forceinline__ void load_chunk(const float* __restrict__ wb,
                                           int g, f2v wch[8][3]) {
#pragma unroll
    for (int t = 0; t < 8; ++t) {
        const int st = g * 8 + t;
        wch[t][0] = *(const f2v*)(wb + st * 8);
        wch[t][1] = *(const f2v*)(wb + st * 8 + 192);
        wch[t][2] = *(const f2v*)(wb + st * 8 + 384);
    }
}

// build 8 A-frags from a chunk
__device__ __forceinline__ void build_chunk(const f2v wch[8][3], i4 afg[8]) {
#pragma unroll
    for (int t = 0; t < 8; ++t) {
        u32 lo0, hi0, lo1, hi1;
        mk_float(wch[t][0].x, wch[t][1].x, wch[t][2].x, lo0, hi0);
        mk_float(wch[t][0].y, wch[t][1].y, wch[t][2].y, lo1, hi1);
        i4 v; v.x = (int)lo0; v.y = (int)hi0; v.z = (int)lo1; v.w = (int)hi1;
        afg[t] = v;
    }
}

// ---- phase A: 12 consecutive G starting at 9*ci0 + R0 for position-lane p.
template <int R0>
__device__ __forceinline__ void phaseA_12(const float* __restrict__ xt,
                                          u32* __restrict__ yb,
                                          int ci0, int p) {
#pragma unroll
    for (int d = 0; d < 12; ++d) {
        const int r    = (R0 + d) % 9;
        const int cinc = (R0 + d) / 9;              // 0 or 1
        const int uv1 = r;           const int cA = 0;
        const int uv2 = (r + 3) % 9; const int cB = 21 + (r + 3) / 9;
        const int uv3 = (r + 6) % 9; const int cC = 42 + (r + 6) / 9;
        const int ci = ci0 + cinc;
        const float x1 = xt[(uv1 / 3) * PLANE + (ci + cA) * HS + p + (uv1 % 3)];
        const float x2 = xt[(uv2 / 3) * PLANE + (ci + cB) * HS + p + (uv2 % 3)];
        const float x3 = xt[(uv3 / 3) * PLANE + (ci + cC) * HS + p + (uv3 % 3)];
        const float sp = x1 + x2, sm = x1 - x2;
        const float y0 = clip1(sp + x3), y1 = clip1(sp - x3);
        const float y2 = clip1(sm + x3), y3 = clip1(sm - x3);
        hp2 lo = __builtin_amdgcn_cvt_pkrtz(y0, y1);
        hp2 hi = __builtin_amdgcn_cvt_pkrtz(y2, y3);
        uu2 pr;
        pr.x = __builtin_bit_cast(u32, lo);
        pr.y = __builtin_bit_cast(u32, hi);
        const int G = 9 * ci + r;
        *(uu2*)&yb[ybi(G, p)] = pr;                 // ds_write_b64
    }
}

// ---- main: block = 16 positions (1 w-row, h-half) x all 64 channels -------
__global__ __launch_bounds__(256, 2) void maj3_kernel(
        const float* __restrict__ x, const float* __restrict__ w,
        float* __restrict__ out) {
    __shared__ float xt[3 * PLANE];        // 14,592 B : [u:3][c:64][hh:18+pad]
    __shared__ u32  yb[96 * NP * 4];       // 24,576 B : y fp16 [G/2][p][4]

    const int tid   = threadIdx.x;
    const int lane  = tid & 63;
    const int wid   = tid >> 6;
    const int blk   = blockIdx.x;          // 512 = bw*2 + hhalf
    const int hhalf = blk & 1;
    const int bw    = blk >> 1;            // bimg*32 + wrow
    const int bimg  = bw >> 5, wrow = bw & 31;
    const int h0    = hhalf * NP;

    const int p16 = lane & 15, sub = lane >> 4;
    const int a0  = wid * 16;

    // ---- staging loads: burst-issue 14 per thread into regs (R8-identical)
    const int c = lane;
    const float* xb = x + (bimg * 32 * 32) * 64 + c;
    float vs[14];
#pragma unroll
    for (int j = 0; j < 14; ++j) {
        const int i = wid + 4 * j;
        const int u = i / 18, hh = i - u * 18;
        const int wx = wrow - 1 + u, hx = h0 - 1 + hh;
        float v = -1.0f;
        if (i < 54 && (unsigned)wx < 32u && (unsigned)hx < 32u)
            v = xb[(wx * 32 + hx) * 64];
        vs[j] = v;
    }

    // ---- staging writes (R8-identical) -----------------------------------
#pragma unroll
    for (int j = 0; j < 14; ++j) {
        const int i = wid + 4 * j;
        if (i < 54) {
            const int u = i / 18, hh = i - u * 18;
            xt[u * PLANE + c * HS + hh] = vs[j];
        }
    }

    // ---- chunk-0 w loads: 24 f2v, latency hides under phase A ------------
    // lane (p16,sub) owns M[a = a0+p16][G0, G0+1], G0 = st*8 + sub*2:
    // w1 = w[a*576 + G0], w2 = +192, w3 = +384 (compile-time imm offsets).
    const float* wb = w + (a0 + p16) * 576 + sub * 2;
    f2v wA[8][3];
    load_chunk(wb, 0, wA);
    __syncthreads();

    // ---- phase A: 16 (wave,sub) slots x 12 G x 16 positions (R8-identical)
    {
        const int s = wid * 4 + sub;                 // 0..15
        const int ci0 = (4 * s) / 3;                 // = (12s)/9
        const int sel = s % 3;                       // r0 = 3*sel
        if (sel == 0)      phaseA_12<0>(xt, yb, ci0, p16);
        else if (sel == 1) phaseA_12<3>(xt, yb, ci0, p16);
        else               phaseA_12<6>(xt, yb, ci0, p16);
    }
    __syncthreads();

    // ---- phase B: 24 K-steps in 3 chunks; chunk k+1 loads fly under
    // chunk k's build VALU + 8 MFMA + 8 ds_read_b128.
    {
        f4 acc = {0.f, 0.f, 0.f, 0.f};
        f2v wBc[8][3], wCc[8][3];
        i4 afg[8];

        load_chunk(wb, 1, wBc);          // issue chunk 1
        build_chunk(wA, afg);            // build chunk 0 (waits its vmcnt)
#pragma unroll
        for (int t = 0; t < 8; ++t) {
            const int st = t;
            const i4 bi = *(const i4*)&yb[((st * 4 + sub) * NP + p16) * 4];
            acc = __builtin_amdgcn_mfma_f32_16x16x32_f16(
                      __builtin_bit_cast(h8, afg[t]),
                      __builtin_bit_cast(h8, bi), acc, 0, 0, 0);
        }

        load_chunk(wb, 2, wCc);          // issue chunk 2
        build_chunk(wBc, afg);
#pragma unroll
        for (int t = 0; t < 8; ++t) {
            const int st = 8 + t;
            const i4 bi = *(const i4*)&yb[((st * 4 + sub) * NP + p16) * 4];
            acc = __builtin_amdgcn_mfma_f32_16x16x32_f16(
                      __builtin_bit_cast(h8, afg[t]),
                      __builtin_bit_cast(h8, bi), acc, 0, 0, 0);
        }

        build_chunk(wCc, afg);
#pragma unroll
        for (int t = 0; t < 8; ++t) {
            const int st = 16 + t;
            const i4 bi = *(const i4*)&yb[((st * 4 + sub) * NP + p16) * 4];
            acc = __builtin_amdgcn_mfma_f32_16x16x32_f16(
                      __builtin_bit_cast(h8, afg[t]),
                      __builtin_bit_cast(h8, bi), acc, 0, 0, 0);
        }

        // C/D: col = lane&15 = position, row = sub*4+reg = channel (R7-verified)
        const int n = bw * 32 + h0 + p16;
        float* op = out + n * 64 + a0 + sub * 4;
        f4 o;
#pragma unroll
        for (int r = 0; r < 4; ++r) o[r] = 3.0f * acc[r];
        *(f4*)op = o;
    }
}

extern "C" void kernel_launch(void* const* d_in, const int* in_sizes, int n_in,
                              void* d_out, int out_size, void* d_ws, size_t ws_size,
                              hipStream_t stream) {
    const float* x = (const float*)d_in[0];   // (8,32,32,64) f32
    const float* w = (const float*)d_in[1];   // (64,576) f32, exact +/-1.0
    float* out = (float*)d_out;               // (8,32,32,64) f32
    (void)d_ws; (void)ws_size;
    maj3_kernel<<<512, 256, 0, stream>>>(x, w, out);
}

// Round 12
// 65.892 us; speedup vs baseline: 1.1095x; 1.1095x over previous
//
#include <hip/hip_runtime.h>

// Maj3 via 4-class reformulation + MFMA (verified R7/R8):
//   clip(w1x1+w2x2+w3x3) = w1 * clip(x1 + (w1w2)x2 + (w1w3)x3),  w in {+-1}
//   y[n, G*4+q] = clip(x1 +- x2 +- x3)   (fp16);  M[a, G*4+q] = w1 or 0
//   out[n,a] = 3 * sum_k y[n,k] * M[k,a]   -> 16x16x32 f16 MFMA, K=768
// R12: restore R8 (best, 66.2us; R9 occupancy / R10-R11 fusion all lost to
// it) + one micro-fix: dual accumulators halve the 24-deep dependent MFMA
// chain in phase B. Everything else R8-identical.

typedef unsigned int u32;
typedef float f4 __attribute__((ext_vector_type(4)));
typedef _Float16 h8 __attribute__((ext_vector_type(8)));
typedef __fp16 hp2 __attribute__((ext_vector_type(2)));
typedef u32 uu2 __attribute__((ext_vector_type(2)));
typedef int i4 __attribute__((ext_vector_type(4)));

#define HS    19            // h-stride (words) in x tile: odd -> no conflicts
#define PLANE (64 * HS)     // 1216 words per w-plane
#define NP    16            // positions per block

__device__ __forceinline__ float clip1(float s) {
    return __builtin_amdgcn_fmed3f(s, -1.0f, 1.0f);
}

// yb index for (G, p): [(G/2)][p][ (G&1)*2 + {0,1} ]  (16B-aligned per (G/2,p))
__device__ __forceinline__ int ybi(int G, int p) {
    return ((G >> 1) * NP + p) * 4 + (G & 1) * 2;
}

// ---- prep: M[a][k=G*4+q] fp16, stored as u32 pairs: M32[a*384 + G*2 + {0,1}]
__global__ __launch_bounds__(192) void prep_kernel(const float* __restrict__ w,
                                                   u32* __restrict__ M32) {
    const int a = blockIdx.x, G = threadIdx.x;
    const float w1 = w[a * 576 + G];
    const float w2 = w[a * 576 + 192 + G];
    const float w3 = w[a * 576 + 384 + G];
    const int q = ((w1 * w2 < 0.f) ? 2 : 0) + ((w1 * w3 < 0.f) ? 1 : 0);
    const u32 s1 = (w1 < 0.f) ? 0xBC00u : 0x3C00u;   // fp16 -1 : +1
    const u32 v0 = (q == 0) ? s1 : 0u, v1 = (q == 1) ? s1 : 0u;
    const u32 v2 = (q == 2) ? s1 : 0u, v3 = (q == 3) ? s1 : 0u;
    M32[a * 384 + G * 2 + 0] = v0 | (v1 << 16);
    M32[a * 384 + G * 2 + 1] = v2 | (v3 << 16);
}

// ---- phase A: 12 consecutive G starting at 9*ci0 + R0 for position-lane p.
// G = 9*ci + r: U-terms at c-offsets {0, 21+(r+3)/9, 42+(r+6)/9}, uv offsets
// {r, (r+3)%9, (r+6)%9} -- all compile-time per d.
template <int R0>
__device__ __forceinline__ void phaseA_12(const float* __restrict__ xt,
                                          u32* __restrict__ yb,
                                          int ci0, int p) {
#pragma unroll
    for (int d = 0; d < 12; ++d) {
        const int r    = (R0 + d) % 9;
        const int cinc = (R0 + d) / 9;              // 0 or 1
        const int uv1 = r;           const int cA = 0;
        const int uv2 = (r + 3) % 9; const int cB = 21 + (r + 3) / 9;
        const int uv3 = (r + 6) % 9; const int cC = 42 + (r + 6) / 9;
        const int ci = ci0 + cinc;
        const float x1 = xt[(uv1 / 3) * PLANE + (ci + cA) * HS + p + (uv1 % 3)];
        const float x2 = xt[(uv2 / 3) * PLANE + (ci + cB) * HS + p + (uv2 % 3)];
        const float x3 = xt[(uv3 / 3) * PLANE + (ci + cC) * HS + p + (uv3 % 3)];
        const float sp = x1 + x2, sm = x1 - x2;
        const float y0 = clip1(sp + x3), y1 = clip1(sp - x3);
        const float y2 = clip1(sm + x3), y3 = clip1(sm - x3);
        hp2 lo = __builtin_amdgcn_cvt_pkrtz(y0, y1);
        hp2 hi = __builtin_amdgcn_cvt_pkrtz(y2, y3);
        uu2 pr;
        pr.x = __builtin_bit_cast(u32, lo);
        pr.y = __builtin_bit_cast(u32, hi);
        const int G = 9 * ci + r;
        *(uu2*)&yb[ybi(G, p)] = pr;                 // ds_write_b64, 8B aligned
    }
}

// ---- main: block = 16 positions (1 w-row, h-half) x all 64 channels -------
__global__ __launch_bounds__(256, 2) void maj3_kernel(
        const float* __restrict__ x, const u32* __restrict__ M32,
        float* __restrict__ out) {
    __shared__ float xt[3 * PLANE];        // 14,592 B : [u:3][c:64][hh:18+pad]
    __shared__ u32  yb[96 * NP * 4];       // 24,576 B : y fp16 [G/2][p][4]

    const int tid   = threadIdx.x;
    const int lane  = tid & 63;
    const int wid   = tid >> 6;
    const int blk   = blockIdx.x;          // 512 = bw*2 + hhalf
    const int hhalf = blk & 1;
    const int bw    = blk >> 1;            // bimg*32 + wrow
    const int bimg  = bw >> 5, wrow = bw & 31;
    const int h0    = hhalf * NP;

    const int p16 = lane & 15, sub = lane >> 4;
    const int a0  = wid * 16;

    // ---- staging loads: burst-issue 14 per thread into regs --------------
    // task i = wid + 4*j covers 0..55 (guard i<54): u = i/18, hh = i%18
    const int c = lane;
    const float* xb = x + (bimg * 32 * 32) * 64 + c;
    float vs[14];
#pragma unroll
    for (int j = 0; j < 14; ++j) {
        const int i = wid + 4 * j;
        const int u = i / 18, hh = i - u * 18;
        const int wx = wrow - 1 + u, hx = h0 - 1 + hh;
        float v = -1.0f;
        if (i < 54 && (unsigned)wx < 32u && (unsigned)hx < 32u)
            v = xb[(wx * 32 + hx) * 64];
        vs[j] = v;
    }

    // ---- hoisted M prefetch: issue now, consumed in phase B --------------
    // A-frag: lane reads M[a0+p16][u32 idx = sub*4 + st*16 + 0..3]
    const u32* mp = M32 + (a0 + p16) * 384 + sub * 4;
    i4 af[24];
#pragma unroll
    for (int st = 0; st < 24; ++st)
        af[st] = *(const i4*)(mp + st * 16);

    // ---- staging writes ---------------------------------------------------
#pragma unroll
    for (int j = 0; j < 14; ++j) {
        const int i = wid + 4 * j;
        if (i < 54) {
            const int u = i / 18, hh = i - u * 18;
            xt[u * PLANE + c * HS + hh] = vs[j];
        }
    }
    __syncthreads();

    // ---- phase A: 16 (wave,sub) slots x 12 G x 16 positions ---------------
    {
        const int s = wid * 4 + sub;                 // 0..15
        const int ci0 = (4 * s) / 3;                 // = (12s)/9
        const int sel = s % 3;                       // r0 = 3*sel
        if (sel == 0)      phaseA_12<0>(xt, yb, ci0, p16);
        else if (sel == 1) phaseA_12<3>(xt, yb, ci0, p16);
        else               phaseA_12<6>(xt, yb, ci0, p16);
    }
    __syncthreads();

    // ---- phase B: 24 K-steps of 16x16x32 f16; B-frag = one ds_read_b128 ---
    // dual accumulators: halve the dependent-MFMA chain (12 deep each)
    {
        f4 acc0 = {0.f, 0.f, 0.f, 0.f};
        f4 acc1 = {0.f, 0.f, 0.f, 0.f};
#pragma unroll
        for (int st = 0; st < 24; st += 2) {
            // Ga = st*8 + sub*2 -> (Ga>>1) = st*4 + sub; 4 u32 contiguous
            const i4 bi0 = *(const i4*)&yb[((st * 4 + sub) * NP + p16) * 4];
            const i4 bi1 = *(const i4*)&yb[(((st + 1) * 4 + sub) * NP + p16) * 4];
            acc0 = __builtin_amdgcn_mfma_f32_16x16x32_f16(
                       __builtin_bit_cast(h8, af[st]),
                       __builtin_bit_cast(h8, bi0), acc0, 0, 0, 0);
            acc1 = __builtin_amdgcn_mfma_f32_16x16x32_f16(
                       __builtin_bit_cast(h8, af[st + 1]),
                       __builtin_bit_cast(h8, bi1), acc1, 0, 0, 0);
        }

        // C/D: col = lane&15 = position, row = sub*4+reg = channel (verified R7)
        const int n = bw * 32 + h0 + p16;
        float* op = out + n * 64 + a0 + sub * 4;
        f4 o;
#pragma unroll
        for (int r = 0; r < 4; ++r) o[r] = 3.0f * (acc0[r] + acc1[r]);
        *(f4*)op = o;
    }
}

extern "C" void kernel_launch(void* const* d_in, const int* in_sizes, int n_in,
                              void* d_out, int out_size, void* d_ws, size_t ws_size,
                              hipStream_t stream) {
    const float* x = (const float*)d_in[0];   // (8,32,32,64) f32
    const float* w = (const float*)d_in[1];   // (64,576) f32, exact +/-1.0
    float* out = (float*)d_out;               // (8,32,32,64) f32
    u32* M32 = (u32*)d_ws;                    // 98,304 B used
    prep_kernel<<<64, 192, 0, stream>>>(w, M32);
    maj3_kernel<<<512, 256, 0, stream>>>(x, M32, out);
}